// Round 1
// baseline (54.642 us; speedup 1.0000x reference)
//
#include <hip/hip_runtime.h>
#include <math.h>

#define Bn 64
#define Ln 350
#define Kn 8
#define Dn 300
#define Cn 20
#define SPLIT 32
#define PAD_IDX 1
#define NEG_BIG (-1e18f)

// ---------------------------------------------------------------------------
// Kernel A: per (b,l): M[d] = max_k( mask(ew[k]*nbr[k,d]) ), combined =
// (1-ir)*M + ir*node_emb, accumulate sum over l into s[b][d] (fp32 ws).
// Block = 256 threads (4 waves). Block (b, sidx) covers l in {sidx + 32*j}.
// Wave w takes j = w, w+4, w+8, ... Each lane handles float4 quad `lane`
// (d = 4*lane .. 4*lane+3) and, for lane < 11, quad lane+64 (d = 256..299).
// ---------------------------------------------------------------------------
__global__ __launch_bounds__(256) void mp_reduce(
    const int* __restrict__ node_sets,
    const float* __restrict__ emb_node,
    const float* __restrict__ edge_w,
    const float* __restrict__ emb_nbr,
    const float* __restrict__ info_rate,
    float* __restrict__ s_out)
{
    __shared__ __align__(16) float sAcc[4][Dn + 4];

    const int bid  = blockIdx.x;
    const int b    = bid / SPLIT;
    const int sidx = bid % SPLIT;
    const int tid  = threadIdx.x;
    const int wave = tid >> 6;
    const int lane = tid & 63;
    const bool has1 = (lane < (Dn / 4 - 64));   // 75 quads total; 11 in tail

    float4 acc0 = make_float4(0.f, 0.f, 0.f, 0.f);
    float4 acc1 = make_float4(0.f, 0.f, 0.f, 0.f);

    for (int j = wave;; j += 4) {
        const int l = sidx + j * SPLIT;
        if (l >= Ln) break;
        const size_t row = (size_t)b * Ln + l;

        // wave-uniform scalars (broadcast loads, L1/L2-cached)
        const float* ewp = edge_w + row * Kn;
        float ewv[Kn];
        #pragma unroll
        for (int k = 0; k < Kn; ++k) ewv[k] = ewp[k];

        const int node = node_sets[row];
        const float ir = (node == PAD_IDX) ? 1.0f : info_rate[node];
        const float om = 1.0f - ir;

        const float* nb = emb_nbr + row * (size_t)(Kn * Dn);
        const float* en = emb_node + row * (size_t)Dn;

        // ---- quad 0: d = 4*lane .. 4*lane+3 (covers d < 256)
        {
            float4 m = make_float4(NEG_BIG, NEG_BIG, NEG_BIG, NEG_BIG);
            #pragma unroll
            for (int k = 0; k < Kn; ++k) {
                const float4 v = *reinterpret_cast<const float4*>(nb + k * Dn + 4 * lane);
                const float w = ewv[k];
                float x0 = w * v.x, x1 = w * v.y, x2 = w * v.z, x3 = w * v.w;
                x0 = (x0 == 0.f) ? NEG_BIG : x0;
                x1 = (x1 == 0.f) ? NEG_BIG : x1;
                x2 = (x2 == 0.f) ? NEG_BIG : x2;
                x3 = (x3 == 0.f) ? NEG_BIG : x3;
                m.x = fmaxf(m.x, x0);
                m.y = fmaxf(m.y, x1);
                m.z = fmaxf(m.z, x2);
                m.w = fmaxf(m.w, x3);
            }
            const float4 e = *reinterpret_cast<const float4*>(en + 4 * lane);
            acc0.x += om * m.x + ir * e.x;
            acc0.y += om * m.y + ir * e.y;
            acc0.z += om * m.z + ir * e.z;
            acc0.w += om * m.w + ir * e.w;
        }

        // ---- quad 1: d = 256 + 4*lane .. +3 (lanes 0..10 only)
        if (has1) {
            const int off = 256 + 4 * lane;
            float4 m = make_float4(NEG_BIG, NEG_BIG, NEG_BIG, NEG_BIG);
            #pragma unroll
            for (int k = 0; k < Kn; ++k) {
                const float4 v = *reinterpret_cast<const float4*>(nb + k * Dn + off);
                const float w = ewv[k];
                float x0 = w * v.x, x1 = w * v.y, x2 = w * v.z, x3 = w * v.w;
                x0 = (x0 == 0.f) ? NEG_BIG : x0;
                x1 = (x1 == 0.f) ? NEG_BIG : x1;
                x2 = (x2 == 0.f) ? NEG_BIG : x2;
                x3 = (x3 == 0.f) ? NEG_BIG : x3;
                m.x = fmaxf(m.x, x0);
                m.y = fmaxf(m.y, x1);
                m.z = fmaxf(m.z, x2);
                m.w = fmaxf(m.w, x3);
            }
            const float4 e = *reinterpret_cast<const float4*>(en + off);
            acc1.x += om * m.x + ir * e.x;
            acc1.y += om * m.y + ir * e.y;
            acc1.z += om * m.z + ir * e.z;
            acc1.w += om * m.w + ir * e.w;
        }
    }

    // per-wave partials -> LDS (disjoint rows, no conflicts)
    *reinterpret_cast<float4*>(&sAcc[wave][4 * lane]) = acc0;
    if (has1) *reinterpret_cast<float4*>(&sAcc[wave][256 + 4 * lane]) = acc1;
    __syncthreads();

    // block reduce over 4 waves, one atomicAdd per (b,d) per block
    for (int d = tid; d < Dn; d += 256) {
        const float sum = sAcc[0][d] + sAcc[1][d] + sAcc[2][d] + sAcc[3][d];
        atomicAdd(&s_out[b * Dn + d], sum);
    }
}

// ---------------------------------------------------------------------------
// Kernel B: x[b,c] = relu(dot(s[b,:], W[c,:]) + bias[c]); softmax over C=20.
// One block per b; tiny.
// ---------------------------------------------------------------------------
__global__ __launch_bounds__(64) void mp_head(
    const float* __restrict__ s_in,
    const float* __restrict__ Wm,
    const float* __restrict__ bias,
    float* __restrict__ out)
{
    __shared__ float ssh[Dn];
    __shared__ float xsh[Cn];

    const int b = blockIdx.x;
    const int t = threadIdx.x;

    for (int d = t; d < Dn; d += 64) ssh[d] = s_in[b * Dn + d];
    __syncthreads();

    if (t < Cn) {
        float acc = bias[t];
        const float* wr = Wm + t * Dn;
        for (int d = 0; d < Dn; ++d) acc += ssh[d] * wr[d];
        xsh[t] = fmaxf(acc, 0.f);
    }
    __syncthreads();

    if (t < Cn) {
        float mx = xsh[0];
        #pragma unroll
        for (int i = 1; i < Cn; ++i) mx = fmaxf(mx, xsh[i]);
        float sum = 0.f;
        #pragma unroll
        for (int i = 0; i < Cn; ++i) sum += expf(xsh[i] - mx);
        out[b * Cn + t] = expf(xsh[t] - mx) / sum;
    }
}

extern "C" void kernel_launch(void* const* d_in, const int* in_sizes, int n_in,
                              void* d_out, int out_size, void* d_ws, size_t ws_size,
                              hipStream_t stream) {
    const int*   node_sets = (const int*)d_in[0];
    const float* emb_node  = (const float*)d_in[1];
    const float* edge_w    = (const float*)d_in[2];
    const float* emb_nbr   = (const float*)d_in[3];
    const float* info_rate = (const float*)d_in[4];
    const float* Wm        = (const float*)d_in[5];
    const float* bias      = (const float*)d_in[6];
    float* out  = (float*)d_out;
    float* s_ws = (float*)d_ws;  // [Bn][Dn] fp32 accumulator

    hipMemsetAsync(d_ws, 0, (size_t)Bn * Dn * sizeof(float), stream);

    mp_reduce<<<dim3(Bn * SPLIT), 256, 0, stream>>>(
        node_sets, emb_node, edge_w, emb_nbr, info_rate, s_ws);

    mp_head<<<dim3(Bn), 64, 0, stream>>>(s_ws, Wm, bias, out);
}